// Round 14
// baseline (478.925 us; speedup 1.0000x reference)
//
#include <hip/hip_runtime.h>
#include <math.h>

typedef unsigned short u16;
typedef unsigned int u32;
typedef __attribute__((ext_vector_type(8))) short bf16x8;
typedef __attribute__((ext_vector_type(8))) unsigned short u16x8;
typedef __attribute__((ext_vector_type(4))) float f32x4;
typedef __attribute__((ext_vector_type(4))) unsigned int u32x4;

__device__ __forceinline__ u16 f2bf(float f){
  union { float f; unsigned u; } c; c.f = f;
  unsigned u = c.u;
  return (u16)((u + 0x7fffu + ((u >> 16) & 1u)) >> 16);
}
__device__ __forceinline__ float bf2f(u16 h){
  union { unsigned u; float f; } c; c.u = ((unsigned)h) << 16;
  return c.f;
}
__device__ __forceinline__ u32 pack2(float lo, float hi){
  return (u32)f2bf(lo) | ((u32)f2bf(hi) << 16);
}
__device__ __forceinline__ void gload_lds16(const void* g, void* l){
  __builtin_amdgcn_global_load_lds((const __attribute__((address_space(1))) void*)g,
                                   (__attribute__((address_space(3))) void*)l, 16, 0, 0);
}
// XOR swizzle within a 1024B LDS row (attention V^T)
__device__ __forceinline__ int swz(int row, int bc){
  return (row << 10) + (bc ^ ((row & 7) << 4));
}

#define BAR() asm volatile("s_barrier" ::: "memory")

// ---------------- weight transpose + f32->bf16 : in [K][N] f32 -> out [N][K] bf16
__global__ void transpose_cvt(const float* __restrict__ in, u16* __restrict__ out, int K, int N){
  __shared__ float tile[32][33];
  int n0 = blockIdx.x << 5, k0 = blockIdx.y << 5;
  int tx = threadIdx.x, ty = threadIdx.y;
  #pragma unroll
  for (int r = 0; r < 32; r += 8)
    tile[ty + r][tx] = in[(size_t)(k0 + ty + r) * N + n0 + tx];
  __syncthreads();
  #pragma unroll
  for (int r = 0; r < 32; r += 8)
    out[(size_t)(n0 + ty + r) * K + k0 + tx] = f2bf(tile[tx][ty + r]);
}

__global__ void concat3(const float* __restrict__ a, const float* __restrict__ b,
                        const float* __restrict__ c, float* __restrict__ o){
  int i = blockIdx.x * 256 + threadIdx.x;
  o[i] = i < 1024 ? a[i] : (i < 2048 ? b[i - 1024] : c[i - 2048]);
}

// ---------------- layernorm: f32 [rows][1024] -> bf16 [rows][1024]
__device__ __forceinline__ float blockReduce(float v, float* ws){
  #pragma unroll
  for (int m = 1; m < 64; m <<= 1) v += __shfl_xor(v, m, 64);
  int w = threadIdx.x >> 6;
  __syncthreads();
  if ((threadIdx.x & 63) == 0) ws[w] = v;
  __syncthreads();
  return ws[0] + ws[1] + ws[2] + ws[3];
}

struct U16x4 { u16 x, y, z, w; };

__global__ __launch_bounds__(256) void ln_kernel(const float* __restrict__ in, const float* __restrict__ g,
    const float* __restrict__ be, u16* __restrict__ out){
  __shared__ float ws[4];
  int row = blockIdx.x;
  const float4 v = ((const float4*)(in + ((size_t)row << 10)))[threadIdx.x];
  float s = v.x + v.y + v.z + v.w;
  s = blockReduce(s, ws);
  float mean = s * (1.f / 1024.f);
  float dx = v.x - mean, dy = v.y - mean, dz = v.z - mean, dw = v.w - mean;
  float s2 = dx*dx + dy*dy + dz*dz + dw*dw;
  s2 = blockReduce(s2, ws);
  float rstd = rsqrtf(s2 * (1.f / 1024.f) + 1e-5f);
  float4 gv = ((const float4*)g)[threadIdx.x];
  float4 bv = ((const float4*)be)[threadIdx.x];
  U16x4 ov;
  ov.x = f2bf(dx * rstd * gv.x + bv.x);
  ov.y = f2bf(dy * rstd * gv.y + bv.y);
  ov.z = f2bf(dz * rstd * gv.z + bv.z);
  ov.w = f2bf(dw * rstd * gv.w + bv.w);
  ((U16x4*)(out + ((size_t)row << 10)))[threadIdx.x] = ov;
}

// ================= 256x256 8-phase bf16 GEMM (unchanged) =========
template<int QM, int QN, int LB, int RDA, int WAIT, typename F>
__device__ __forceinline__ void ph256(const char* lds, const int (&aoff)[2], const int (&boff)[2],
    bf16x8 (&af)[4][2], bf16x8 (&bv)[2][2], f32x4 (&acc)[8][4], F&& stg){
  if constexpr (RDA) {
    const char* Ar = lds + LB*65536 + QM*16384;
    #pragma unroll
    for (int fi = 0; fi < 4; ++fi)
      #pragma unroll
      for (int ks = 0; ks < 2; ++ks)
        af[fi][ks] = *(const bf16x8*)(Ar + fi*2048 + aoff[ks]);
  }
  {
    const char* Br = lds + LB*65536 + 32768 + QN*16384;
    #pragma unroll
    for (int fj = 0; fj < 2; ++fj)
      #pragma unroll
      for (int ks = 0; ks < 2; ++ks)
        bv[fj][ks] = *(const bf16x8*)(Br + fj*2048 + boff[ks]);
  }
  stg();
  BAR();
  asm volatile("s_waitcnt lgkmcnt(0)" ::: "memory");
  __builtin_amdgcn_sched_barrier(0);
  __builtin_amdgcn_s_setprio(1);
  #pragma unroll
  for (int fi = 0; fi < 4; ++fi)
    #pragma unroll
    for (int fj = 0; fj < 2; ++fj){
      acc[QM*4+fi][QN*2+fj] = __builtin_amdgcn_mfma_f32_16x16x32_bf16(af[fi][0], bv[fj][0], acc[QM*4+fi][QN*2+fj], 0, 0, 0);
      acc[QM*4+fi][QN*2+fj] = __builtin_amdgcn_mfma_f32_16x16x32_bf16(af[fi][1], bv[fj][1], acc[QM*4+fi][QN*2+fj], 0, 0, 0);
    }
  __builtin_amdgcn_s_setprio(0);
  if constexpr (WAIT >= 0)
    asm volatile("s_waitcnt vmcnt(%0)" :: "n"(WAIT) : "memory");
  BAR();
}

// EPI 0: bf16 scatter to q/k/v [3][B*NH, S, HD] (+bias)
// EPI 2: bf16 = gelu(acc + bias)
template<int EPI>
__global__ __launch_bounds__(512, 2) void gemm8(
    const u16* __restrict__ A, const u16* __restrict__ Bt,
    const float* __restrict__ bias, const float* __restrict__ add,
    void* __restrict__ out, int M, int N, int K)
{
  __shared__ char lds[147456];
  const int NT = K >> 6;
  const int NI = NT >> 1;
  const int nbx = N >> 8;
  const int nwg = gridDim.x, orig = blockIdx.x;
  const int q = nwg >> 3, r = nwg & 7, x = orig & 7;
  const int wg = (x < r ? x * (q + 1) : r * (q + 1) + (x - r) * q) + (orig >> 3);
  const int bx = wg % nbx, by = wg / nbx;
  const int m0 = by << 8, n0 = bx << 8;

  const int tid = threadIdx.x, wave = tid >> 6, lane = tid & 63;
  const int wr = (wave >> 2) & 1, wc = wave & 3;
  const int lcol = lane & 15, lrow4 = lane >> 4;

  int aoff[2], boff[2];
  #pragma unroll
  for (int ks = 0; ks < 2; ++ks){
    const int chunk = (ks*4 + lrow4) ^ (lane & 7);
    aoff[ks] = (wr*64 + lcol)*128 + chunk*16;
    boff[ks] = (wc*32 + lcol)*128 + chunk*16;
  }

  auto STAGE = [&](const u16* Mat, int rbase, int isB, int h, int tt){
    const int rb = (tt < NT) ? ((tt & 1) * 65536 + isB * 32768 + h * 16384) : 131072;
    const int tc = (tt < NT) ? tt : NT - 1;
    #pragma unroll
    for (int s = 0; s < 2; ++s){
      const int o = (tid + s*512) << 4;
      const int row = o >> 7;
      const int c = (o >> 4) & 7;
      const char* src = (const char*)(Mat + (size_t)(rbase + h*128 + row) * K + (size_t)tc * 64)
                        + ((c ^ (row & 7)) << 4);
      gload_lds16(src, (char*)lds + rb + o);
    }
  };

  f32x4 acc[8][4] = {};
  bf16x8 af[4][2], bv[2][2];

  STAGE(A,  m0, 0, 0, 0);
  STAGE(Bt, n0, 1, 0, 0);
  STAGE(A,  m0, 0, 1, 0);
  STAGE(Bt, n0, 1, 1, 0);
  STAGE(A,  m0, 0, 0, 1);
  STAGE(Bt, n0, 1, 1, 1);
  STAGE(A,  m0, 0, 1, 1);
  asm volatile("s_waitcnt vmcnt(6)" ::: "memory");
  BAR();

  for (int i = 0; i < NI; ++i) {
    const int T = 2*i;
    ph256<0, 0, 0, 1, -1>(lds, aoff, boff, af, bv, acc, [&]{ STAGE(Bt, n0, 1, 0, T+1); });
    ph256<0, 1, 0, 0, -1>(lds, aoff, boff, af, bv, acc, [&]{ STAGE(A,  m0, 0, 0, T+2); });
    ph256<1, 1, 0, 1, -1>(lds, aoff, boff, af, bv, acc, [&]{});
    ph256<1, 0, 0, 0,  4>(lds, aoff, boff, af, bv, acc, [&]{ STAGE(Bt, n0, 1, 1, T+2); });
    ph256<0, 0, 1, 1, -1>(lds, aoff, boff, af, bv, acc, [&]{ STAGE(Bt, n0, 1, 0, T+2); });
    ph256<0, 1, 1, 0, -1>(lds, aoff, boff, af, bv, acc, [&]{ STAGE(A,  m0, 0, 1, T+2); });
    ph256<1, 1, 1, 1, -1>(lds, aoff, boff, af, bv, acc, [&]{ STAGE(A,  m0, 0, 0, T+3); });
    ph256<1, 0, 1, 0,  6>(lds, aoff, boff, af, bv, acc, [&]{ STAGE(Bt, n0, 1, 1, T+3); STAGE(A, m0, 0, 1, T+3); });
  }

  { size_t bp = (size_t)bias, ap = (size_t)add;
    asm volatile("" : "+v"(bp), "+v"(ap));
    bias = (const float*)bp; add = (const float*)ap; }

  #pragma unroll
  for (int mi = 0; mi < 8; ++mi) {
    const int gmb = m0 + (mi>>2)*128 + wr*64 + (mi&3)*16 + lrow4*4;
    #pragma unroll
    for (int ni = 0; ni < 4; ++ni) {
      const int gn = n0 + (ni>>1)*128 + wc*32 + (ni&1)*16 + lcol;
      const float bs = bias[gn];
      #pragma unroll
      for (int rr = 0; rr < 4; ++rr) {
        const int gm = gmb + rr;
        float v = acc[mi][ni][rr] + bs;
        if constexpr (EPI == 0) {
          const int which = gn >> 10, g = gn & 1023;
          const int b = gm >> 11, s = gm & 2047;
          const int h = g >> 6, d = g & 63;
          ((u16*)out)[(size_t)which * 8388608 + ((((size_t)((b << 4) + h) << 11) + s) << 6) + d] = f2bf(v);
        } else {
          ((u16*)out)[(size_t)gm * N + gn] = f2bf(0.5f * v * (1.f + erff(v * 0.70710678118f)));
        }
      }
    }
  }
}

// ================= 128x256 4-phase bf16 GEMM (wide, unchanged) ====
template<int QN, int LB, int RDA, int WAIT, typename F>
__device__ __forceinline__ void phW(const char* lds, const int (&aoff)[2], const int (&boff)[2],
    bf16x8 (&af)[4][2], bf16x8 (&bv)[2][2], f32x4 (&acc)[4][4], F&& stg){
  if constexpr (RDA) {
    const char* Ar = lds + LB*49152;
    #pragma unroll
    for (int fi = 0; fi < 4; ++fi)
      #pragma unroll
      for (int ks = 0; ks < 2; ++ks)
        af[fi][ks] = *(const bf16x8*)(Ar + fi*2048 + aoff[ks]);
  }
  {
    const char* Br = lds + LB*49152 + 16384 + QN*16384;
    #pragma unroll
    for (int fj = 0; fj < 2; ++fj)
      #pragma unroll
      for (int ks = 0; ks < 2; ++ks)
        bv[fj][ks] = *(const bf16x8*)(Br + fj*2048 + boff[ks]);
  }
  stg();
  BAR();
  asm volatile("s_waitcnt lgkmcnt(0)" ::: "memory");
  __builtin_amdgcn_sched_barrier(0);
  __builtin_amdgcn_s_setprio(1);
  #pragma unroll
  for (int fi = 0; fi < 4; ++fi)
    #pragma unroll
    for (int fj = 0; fj < 2; ++fj){
      acc[fi][QN*2+fj] = __builtin_amdgcn_mfma_f32_16x16x32_bf16(af[fi][0], bv[fj][0], acc[fi][QN*2+fj], 0, 0, 0);
      acc[fi][QN*2+fj] = __builtin_amdgcn_mfma_f32_16x16x32_bf16(af[fi][1], bv[fj][1], acc[fi][QN*2+fj], 0, 0, 0);
    }
  __builtin_amdgcn_s_setprio(0);
  if constexpr (WAIT >= 0)
    asm volatile("s_waitcnt vmcnt(%0)" :: "n"(WAIT) : "memory");
  BAR();
}

__global__ __launch_bounds__(512, 2) void gemmW(
    const u16* __restrict__ A, const u16* __restrict__ Bt,
    const float* __restrict__ bias, const float* __restrict__ add,
    float* __restrict__ out, int M, int N, int K)
{
  __shared__ char lds[106496];
  const int NT = K >> 6;
  const int NI = NT >> 1;
  const int nbx = N >> 8;
  const int nwg = gridDim.x, orig = blockIdx.x;
  const int q = nwg >> 3, r = nwg & 7, x = orig & 7;
  const int wg = (x < r ? x * (q + 1) : r * (q + 1) + (x - r) * q) + (orig >> 3);
  const int bx = wg % nbx, by = wg / nbx;
  const int m0 = by << 7, n0 = bx << 8;

  const int tid = threadIdx.x, wave = tid >> 6, lane = tid & 63;
  const int wr = wave >> 2, wc = wave & 3;
  const int lcol = lane & 15, lrow4 = lane >> 4;

  int aoff[2], boff[2];
  #pragma unroll
  for (int ks = 0; ks < 2; ++ks){
    const int chunk = (ks*4 + lrow4) ^ (lane & 7);
    aoff[ks] = (wr*64 + lcol)*128 + chunk*16;
    boff[ks] = (wc*32 + lcol)*128 + chunk*16;
  }

  auto STAGE = [&](const u16* Mat, int rbase, int kind, int tt){
    const int rb = (tt < NT) ? ((tt & 1) * 49152 + kind * 16384) : 98304;
    const int tc = (tt < NT) ? tt : NT - 1;
    #pragma unroll
    for (int s = 0; s < 2; ++s){
      const int o = (tid + s*512) << 4;
      const int row = o >> 7;
      const int c = (o >> 4) & 7;
      const char* src = (const char*)(Mat + (size_t)(rbase + row) * K + (size_t)tc * 64)
                        + ((c ^ (row & 7)) << 4);
      gload_lds16(src, (char*)lds + rb + o);
    }
  };

  f32x4 acc[4][4] = {};
  bf16x8 af[4][2], bv[2][2];

  STAGE(A,  m0,       0, 0);
  STAGE(Bt, n0,       1, 0);
  STAGE(Bt, n0 + 128, 2, 0);
  STAGE(A,  m0,       0, 1);
  STAGE(Bt, n0,       1, 1);
  asm volatile("s_waitcnt vmcnt(4)" ::: "memory");
  BAR();

  for (int i = 0; i < NI; ++i) {
    const int T = 2*i;
    phW<0, 0, 1, -1>(lds, aoff, boff, af, bv, acc, [&]{ STAGE(Bt, n0 + 128, 2, T+1); });
    phW<1, 0, 0,  4>(lds, aoff, boff, af, bv, acc, [&]{ STAGE(A, m0, 0, T+2); STAGE(Bt, n0, 1, T+2); });
    phW<0, 1, 1, -1>(lds, aoff, boff, af, bv, acc, [&]{ STAGE(Bt, n0 + 128, 2, T+2); });
    phW<1, 1, 0,  4>(lds, aoff, boff, af, bv, acc, [&]{ STAGE(A, m0, 0, T+3); STAGE(Bt, n0, 1, T+3); });
  }

  { size_t bp = (size_t)bias, ap = (size_t)add;
    asm volatile("" : "+v"(bp), "+v"(ap));
    bias = (const float*)bp; add = (const float*)ap; }

  #pragma unroll
  for (int fi = 0; fi < 4; ++fi) {
    const int gmb = m0 + wr*64 + fi*16 + lrow4*4;
    #pragma unroll
    for (int j = 0; j < 4; ++j) {
      const int gn = n0 + (j>>1)*128 + wc*32 + (j&1)*16 + lcol;
      const float bs = bias[gn];
      #pragma unroll
      for (int rr = 0; rr < 4; ++rr) {
        const int gm = gmb + rr;
        out[(size_t)gm * N + gn] = acc[fi][j][rr] + bs + add[(size_t)gm * N + gn];
      }
    }
  }
}

// ================= windowed attention: eighth-split online softmax, 512 thr ==
// 512 blocks x 512 thr (8 waves), __launch_bounds__(512,2) -> VGPR cap 128;
// demand shrunk to ~110 via SPLIT=4 (acc[4]=16 VGPR) + load batch capped at 2 j.
// LDS = V^T 64KB -> 2 blocks/CU x 2 waves/SIMD = 4 waves/SIMD (2x r12 TLP).
// Even/odd windows -> disjoint parity buffers; merge kernel combines.
template<int NJ>  // NJ = W/16 (24 or 32)
__device__ void attn_core(const u16* __restrict__ Qp, const u16* __restrict__ Kp,
    u16* __restrict__ ctxP, const char* vtb, int start, int widx, int bh)
{
  const int tid = threadIdx.x, wave = tid >> 6, lane = tid & 63;
  const int q = lane & 15, g = lane >> 4;
  constexpr int NSPLIT = NJ / 4;
  const float scale = 0.125f;  // 64^-0.5
  const int b = bh >> 4, h = bh & 15;

  for (int qt = wave; qt < NJ; qt += 8) {
    const int q0 = qt * 16;
    const bf16x8 bq0 = *(const bf16x8*)(Qp + (q0 + q) * 64 + g * 8);
    const bf16x8 bq1 = *(const bf16x8*)(Qp + (q0 + q) * 64 + 32 + g * 8);
    float m = -3.0e38f, l = 0.f;
    f32x4 o[4] = {};
    const int s0 = ((g & 1) << 5) + q;
    const int s1 = s0 + 16;
    const bool lowj = (g < 2);

    #pragma unroll
    for (int hh = 0; hh < NSPLIT; ++hh) {
      // QK^T for this 4x16-key split: acc[j][r] = S[key=(hh*4+j)*16+g*4+r][q]
      f32x4 acc[4];
      #pragma unroll
      for (int j = 0; j < 4; ++j) {
        const int jj = hh * 4 + j;
        bf16x8 k0 = *(const bf16x8*)(Kp + (jj*16 + q) * 64 + g * 8);
        bf16x8 k1 = *(const bf16x8*)(Kp + (jj*16 + q) * 64 + 32 + g * 8);
        f32x4 t = {};
        t = __builtin_amdgcn_mfma_f32_16x16x32_bf16(k0, bq0, t, 0, 0, 0);
        t = __builtin_amdgcn_mfma_f32_16x16x32_bf16(k1, bq1, t, 0, 0, 0);
        acc[j] = t;
        if ((j & 1) == 1) __builtin_amdgcn_sched_barrier(0);  // cap load batch at 2 j
      }
      // running max + flash rescale
      float mh = -3.0e38f;
      #pragma unroll
      for (int j = 0; j < 4; ++j)
        #pragma unroll
        for (int r = 0; r < 4; ++r) mh = fmaxf(mh, acc[j][r]);
      mh = fmaxf(mh, __shfl_xor(mh, 16, 64));
      mh = fmaxf(mh, __shfl_xor(mh, 32, 64));
      const float mn = fmaxf(m, mh);
      const float fr = __expf((m - mn) * scale);   // lane-uniform across g-group
      m = mn;
      l *= fr;
      #pragma unroll
      for (int df = 0; df < 4; ++df)
        #pragma unroll
        for (int r = 0; r < 4; ++r) o[df][r] *= fr;
      #pragma unroll
      for (int j = 0; j < 4; ++j)
        #pragma unroll
        for (int r = 0; r < 4; ++r) {
          float e = __expf((acc[j][r] - mn) * scale);
          acc[j][r] = e;
          l += e;                                   // per-lane partial sum
        }
      // PV over this split's two 32-key windows (in-reg P assembly)
      #pragma unroll
      for (int c = 0; c < 2; ++c) {
        const u32 a0 = pack2(acc[2*c][0],   acc[2*c][1]);
        const u32 b0 = pack2(acc[2*c][2],   acc[2*c][3]);
        const u32 a1 = pack2(acc[2*c+1][0], acc[2*c+1][1]);
        const u32 b1 = pack2(acc[2*c+1][2], acc[2*c+1][3]);
        const u32 A0l = __shfl(a0, s0, 64), A1l = __shfl(a1, s0, 64);
        const u32 B0l = __shfl(b0, s0, 64), B1l = __shfl(b1, s0, 64);
        const u32 A0h = __shfl(a0, s1, 64), A1h = __shfl(a1, s1, 64);
        const u32 B0h = __shfl(b0, s1, 64), B1h = __shfl(b1, s1, 64);
        union { u32 u[4]; bf16x8 v; } pf;
        pf.u[0] = lowj ? A0l : A1l;
        pf.u[1] = lowj ? B0l : B1l;
        pf.u[2] = lowj ? A0h : A1h;
        pf.u[3] = lowj ? B0h : B1h;
        const int cg = hh * 2 + c;
        #pragma unroll
        for (int df = 0; df < 4; ++df) {
          bf16x8 pv = *(const bf16x8*)(vtb + swz(df*16 + q, (cg*32 + g*8) * 2));
          o[df] = __builtin_amdgcn_mfma_f32_16x16x32_bf16(pv, pf.v, o[df], 0, 0, 0);
        }
        __builtin_amdgcn_sched_barrier(0);
      }
    }
    l += __shfl_xor(l, 16, 64);
    l += __shfl_xor(l, 32, 64);
    const float rs = 1.f / l;

    // epilogue: scale on source lane, shfl-transpose so lane (q,g) holds
    // row p(q), dims [g*16,(g+1)*16) = 32B contiguous; pure store to parity buf.
    const int p = start + q0 + q;
    const int rel = p - (widx * 256 - 128);
    const float wgt = (rel < 256) ? ((widx == 0) ? 1.f : (float)rel * (1.f / 255.f))
                                  : ((widx == 7) ? 1.f : (1.f - (float)(rel - 256) * (1.f / 255.f)));
    const float rw = rs * wgt;
    u32 w0[4], w1[4];
    #pragma unroll
    for (int df = 0; df < 4; ++df) {
      w0[df] = pack2(o[df][0] * rw, o[df][1] * rw);
      w1[df] = pack2(o[df][2] * rw, o[df][3] * rw);
    }
    u32 W8[8] = {};
    #pragma unroll
    for (int df = 0; df < 4; ++df)
      #pragma unroll
      for (int sg = 0; sg < 4; ++sg) {
        const u32 t0 = __shfl(w0[df], sg*16 + q, 64);
        const u32 t1 = __shfl(w1[df], sg*16 + q, 64);
        if (g == df) { W8[2*sg] = t0; W8[2*sg+1] = t1; }
      }
    u16* dst = ctxP + ((((size_t)(b << 11) + (size_t)p) << 10) + (h << 6) + (g << 4));
    u32x4 lo = { W8[0], W8[1], W8[2], W8[3] };
    u32x4 hi = { W8[4], W8[5], W8[6], W8[7] };
    *(u32x4*)dst = lo;
    *(u32x4*)(dst + 8) = hi;
  }
}

__global__ __launch_bounds__(512, 2) void attn_kernel(const u16* __restrict__ qg, const u16* __restrict__ kg,
    const u16* __restrict__ vg, u16* __restrict__ ctxE, u16* __restrict__ ctxO){
  __shared__ u16 Vt[32768];   // V^T only: 64KB -> 2 blocks/CU
  const int widx = (int)blockIdx.x >> 6;
  const int bh = blockIdx.x & 63;
  const int i0 = widx << 8;
  int start = i0 - 128; if (start < 0) start = 0;
  int end = i0 + 384;   if (end > 2048) end = 2048;
  const int W = end - start;
  const int tid = threadIdx.x;
  const u16* Qp = qg + (((size_t)bh << 11) + start) * 64;
  const u16* Kp = kg + (((size_t)bh << 11) + start) * 64;
  const u16* Vp = vg + (((size_t)bh << 11) + start) * 64;
  char* vtb = (char*)Vt;
  for (int c = tid; c < W * 8; c += 512) {
    int key = c >> 3, d0 = (c & 7) << 3;
    u16x8 vv = *(const u16x8*)(Vp + key * 64 + d0);
    #pragma unroll
    for (int z = 0; z < 8; ++z)
      *(u16*)(vtb + swz(d0 + z, key * 2)) = vv[z];
  }
  __syncthreads();
  u16* ctxP = (widx & 1) ? ctxO : ctxE;
  if (W == 512) attn_core<32>(Qp, Kp, ctxP, vtb, start, widx, bh);
  else          attn_core<24>(Qp, Kp, ctxP, vtb, start, widx, bh);
}

// merge parity buffers: p<128 -> E; p>=1920 -> O; else E+O. In-place on E is safe.
__global__ __launch_bounds__(256) void merge_kernel(const u16* __restrict__ e,
    const u16* __restrict__ o, u16* __restrict__ out){
  const int i = blockIdx.x * 256 + threadIdx.x;     // u16x8 index
  const int p = (i >> 7) & 2047;                    // (i*8 >> 10) & 2047
  u16x8 ev = ((const u16x8*)e)[i];
  u16x8 ov = ((const u16x8*)o)[i];
  u16x8 r;
  if (p < 128)        r = ev;
  else if (p >= 1920) r = ov;
  else {
    #pragma unroll
    for (int z = 0; z < 8; ++z) r[z] = f2bf(bf2f(ev[z]) + bf2f(ov[z]));
  }
  ((u16x8*)out)[i] = r;
}

// ---------------- host
extern "C" void kernel_launch(void* const* d_in, const int* in_sizes, int n_in,
                              void* d_out, int out_size, void* d_ws, size_t ws_size,
                              hipStream_t stream) {
  const float* hidden = (const float*)d_in[0];
  const float* ln1_g  = (const float*)d_in[1];
  const float* ln1_b  = (const float*)d_in[2];
  const float* wq     = (const float*)d_in[3];
  const float* bq     = (const float*)d_in[4];
  const float* wk     = (const float*)d_in[5];
  const float* bk     = (const float*)d_in[6];
  const float* wv     = (const float*)d_in[7];
  const float* bv     = (const float*)d_in[8];
  const float* wproj  = (const float*)d_in[9];
  const float* bproj  = (const float*)d_in[10];
  const float* ln2_g  = (const float*)d_in[11];
  const float* ln2_b  = (const float*)d_in[12];
  const float* w1     = (const float*)d_in[13];
  const float* b1     = (const float*)d_in[14];
  const float* w2     = (const float*)d_in[15];
  const float* b2     = (const float*)d_in[16];

  char* ws = (char*)d_ws;
  u16* xb    = (u16*)(ws + 0);            // 16 MiB (LN1/LN2 out; ctxO during attn)
  u16* wqkvT = (u16*)(ws + 16777216);     // 6 MiB [3072][1024]
  u16* wpT   = (u16*)(ws + 23068672);     // 2 MiB
  u16* w1T   = (u16*)(ws + 25165824);     // 8 MiB
  u16* w2T   = (u16*)(ws + 33554432);     // 8 MiB
  u16* qb    = (u16*)(ws + 41943040);     // q,k,v contiguous: 3 x 16 MiB
  u16* kb    = (u16*)(ws + 58720256);
  u16* vb    = (u16*)(ws + 75497472);
  u16* ctxE  = (u16*)(ws + 92274688);     // 16 MiB (merged ctx in-place)
  u16* ctxO  = (u16*)(ws + 0);            // aliases xb (dead between qkv and ln2)
  float* bqkv = (float*)(ws + 92274688);  // aliases ctxE start (dead before attn)
  float* res2 = (float*)(ws + 109051904); // 32 MiB f32
  u16* mid   = (u16*)(ws + 41943040);     // 64 MiB, reuses qb..ctx

  dim3 tb(32, 8);
  transpose_cvt<<<dim3(32, 32), tb, 0, stream>>>(wq, wqkvT, 1024, 1024);
  transpose_cvt<<<dim3(32, 32), tb, 0, stream>>>(wk, wqkvT + 1048576, 1024, 1024);
  transpose_cvt<<<dim3(32, 32), tb, 0, stream>>>(wv, wqkvT + 2097152, 1024, 1024);
  transpose_cvt<<<dim3(32, 32), tb, 0, stream>>>(wproj, wpT, 1024, 1024);
  transpose_cvt<<<dim3(128, 32), tb, 0, stream>>>(w1, w1T, 1024, 4096);
  transpose_cvt<<<dim3(32, 128), tb, 0, stream>>>(w2, w2T, 4096, 1024);
  concat3<<<12, 256, 0, stream>>>(bq, bk, bv, bqkv);

  ln_kernel<<<8192, 256, 0, stream>>>(hidden, ln1_g, ln1_b, xb);

  gemm8<0><<<384, 512, 0, stream>>>(xb, wqkvT, bqkv, nullptr, qb, 8192, 3072, 1024);

  attn_kernel<<<512, 512, 0, stream>>>(qb, kb, vb, ctxE, ctxO);
  merge_kernel<<<4096, 256, 0, stream>>>(ctxE, ctxO, ctxE);

  gemmW<<<256, 512, 0, stream>>>(ctxE, wpT, bproj, hidden, res2, 8192, 1024, 1024);

  ln_kernel<<<8192, 256, 0, stream>>>(res2, ln2_g, ln2_b, xb);

  gemm8<2><<<512, 512, 0, stream>>>(xb, w1T, b1, nullptr, mid, 8192, 4096, 1024);
  gemmW<<<256, 512, 0, stream>>>(mid, w2T, b2, res2, (float*)d_out, 8192, 1024, 4096);
}

// Round 15
// 465.164 us; speedup vs baseline: 1.0296x; 1.0296x over previous
//
#include <hip/hip_runtime.h>
#include <math.h>

typedef unsigned short u16;
typedef unsigned int u32;
typedef __attribute__((ext_vector_type(8))) short bf16x8;
typedef __attribute__((ext_vector_type(8))) unsigned short u16x8;
typedef __attribute__((ext_vector_type(4))) float f32x4;
typedef __attribute__((ext_vector_type(4))) unsigned int u32x4;

__device__ __forceinline__ u16 f2bf(float f){
  union { float f; unsigned u; } c; c.f = f;
  unsigned u = c.u;
  return (u16)((u + 0x7fffu + ((u >> 16) & 1u)) >> 16);
}
__device__ __forceinline__ float bf2f(u16 h){
  union { unsigned u; float f; } c; c.u = ((unsigned)h) << 16;
  return c.f;
}
__device__ __forceinline__ u32 pack2(float lo, float hi){
  return (u32)f2bf(lo) | ((u32)f2bf(hi) << 16);
}
__device__ __forceinline__ void gload_lds16(const void* g, void* l){
  __builtin_amdgcn_global_load_lds((const __attribute__((address_space(1))) void*)g,
                                   (__attribute__((address_space(3))) void*)l, 16, 0, 0);
}
// XOR swizzle within a 1024B LDS row (attention V^T)
__device__ __forceinline__ int swz(int row, int bc){
  return (row << 10) + (bc ^ ((row & 7) << 4));
}

#define BAR() asm volatile("s_barrier" ::: "memory")

// ---------------- weight transpose + f32->bf16 : in [K][N] f32 -> out [N][K] bf16
__global__ void transpose_cvt(const float* __restrict__ in, u16* __restrict__ out, int K, int N){
  __shared__ float tile[32][33];
  int n0 = blockIdx.x << 5, k0 = blockIdx.y << 5;
  int tx = threadIdx.x, ty = threadIdx.y;
  #pragma unroll
  for (int r = 0; r < 32; r += 8)
    tile[ty + r][tx] = in[(size_t)(k0 + ty + r) * N + n0 + tx];
  __syncthreads();
  #pragma unroll
  for (int r = 0; r < 32; r += 8)
    out[(size_t)(n0 + ty + r) * K + k0 + tx] = f2bf(tile[tx][ty + r]);
}

__global__ void concat3(const float* __restrict__ a, const float* __restrict__ b,
                        const float* __restrict__ c, float* __restrict__ o){
  int i = blockIdx.x * 256 + threadIdx.x;
  o[i] = i < 1024 ? a[i] : (i < 2048 ? b[i - 1024] : c[i - 2048]);
}

// ---------------- layernorm: f32 [rows][1024] -> bf16 [rows][1024]
__device__ __forceinline__ float blockReduce(float v, float* ws){
  #pragma unroll
  for (int m = 1; m < 64; m <<= 1) v += __shfl_xor(v, m, 64);
  int w = threadIdx.x >> 6;
  __syncthreads();
  if ((threadIdx.x & 63) == 0) ws[w] = v;
  __syncthreads();
  return ws[0] + ws[1] + ws[2] + ws[3];
}

struct U16x4 { u16 x, y, z, w; };

__global__ __launch_bounds__(256) void ln_kernel(const float* __restrict__ in, const float* __restrict__ g,
    const float* __restrict__ be, u16* __restrict__ out){
  __shared__ float ws[4];
  int row = blockIdx.x;
  const float4 v = ((const float4*)(in + ((size_t)row << 10)))[threadIdx.x];
  float s = v.x + v.y + v.z + v.w;
  s = blockReduce(s, ws);
  float mean = s * (1.f / 1024.f);
  float dx = v.x - mean, dy = v.y - mean, dz = v.z - mean, dw = v.w - mean;
  float s2 = dx*dx + dy*dy + dz*dz + dw*dw;
  s2 = blockReduce(s2, ws);
  float rstd = rsqrtf(s2 * (1.f / 1024.f) + 1e-5f);
  float4 gv = ((const float4*)g)[threadIdx.x];
  float4 bv = ((const float4*)be)[threadIdx.x];
  U16x4 ov;
  ov.x = f2bf(dx * rstd * gv.x + bv.x);
  ov.y = f2bf(dy * rstd * gv.y + bv.y);
  ov.z = f2bf(dz * rstd * gv.z + bv.z);
  ov.w = f2bf(dw * rstd * gv.w + bv.w);
  ((U16x4*)(out + ((size_t)row << 10)))[threadIdx.x] = ov;
}

// ================= 256x256 8-phase bf16 GEMM (unchanged) =========
template<int QM, int QN, int LB, int RDA, int WAIT, typename F>
__device__ __forceinline__ void ph256(const char* lds, const int (&aoff)[2], const int (&boff)[2],
    bf16x8 (&af)[4][2], bf16x8 (&bv)[2][2], f32x4 (&acc)[8][4], F&& stg){
  if constexpr (RDA) {
    const char* Ar = lds + LB*65536 + QM*16384;
    #pragma unroll
    for (int fi = 0; fi < 4; ++fi)
      #pragma unroll
      for (int ks = 0; ks < 2; ++ks)
        af[fi][ks] = *(const bf16x8*)(Ar + fi*2048 + aoff[ks]);
  }
  {
    const char* Br = lds + LB*65536 + 32768 + QN*16384;
    #pragma unroll
    for (int fj = 0; fj < 2; ++fj)
      #pragma unroll
      for (int ks = 0; ks < 2; ++ks)
        bv[fj][ks] = *(const bf16x8*)(Br + fj*2048 + boff[ks]);
  }
  stg();
  BAR();
  asm volatile("s_waitcnt lgkmcnt(0)" ::: "memory");
  __builtin_amdgcn_sched_barrier(0);
  __builtin_amdgcn_s_setprio(1);
  #pragma unroll
  for (int fi = 0; fi < 4; ++fi)
    #pragma unroll
    for (int fj = 0; fj < 2; ++fj){
      acc[QM*4+fi][QN*2+fj] = __builtin_amdgcn_mfma_f32_16x16x32_bf16(af[fi][0], bv[fj][0], acc[QM*4+fi][QN*2+fj], 0, 0, 0);
      acc[QM*4+fi][QN*2+fj] = __builtin_amdgcn_mfma_f32_16x16x32_bf16(af[fi][1], bv[fj][1], acc[QM*4+fi][QN*2+fj], 0, 0, 0);
    }
  __builtin_amdgcn_s_setprio(0);
  if constexpr (WAIT >= 0)
    asm volatile("s_waitcnt vmcnt(%0)" :: "n"(WAIT) : "memory");
  BAR();
}

// EPI 0: bf16 scatter to q/k/v [3][B*NH, S, HD] (+bias)
// EPI 2: bf16 = gelu(acc + bias)
template<int EPI>
__global__ __launch_bounds__(512, 2) void gemm8(
    const u16* __restrict__ A, const u16* __restrict__ Bt,
    const float* __restrict__ bias, const float* __restrict__ add,
    void* __restrict__ out, int M, int N, int K)
{
  __shared__ char lds[147456];
  const int NT = K >> 6;
  const int NI = NT >> 1;
  const int nbx = N >> 8;
  const int nwg = gridDim.x, orig = blockIdx.x;
  const int q = nwg >> 3, r = nwg & 7, x = orig & 7;
  const int wg = (x < r ? x * (q + 1) : r * (q + 1) + (x - r) * q) + (orig >> 3);
  const int bx = wg % nbx, by = wg / nbx;
  const int m0 = by << 8, n0 = bx << 8;

  const int tid = threadIdx.x, wave = tid >> 6, lane = tid & 63;
  const int wr = (wave >> 2) & 1, wc = wave & 3;
  const int lcol = lane & 15, lrow4 = lane >> 4;

  int aoff[2], boff[2];
  #pragma unroll
  for (int ks = 0; ks < 2; ++ks){
    const int chunk = (ks*4 + lrow4) ^ (lane & 7);
    aoff[ks] = (wr*64 + lcol)*128 + chunk*16;
    boff[ks] = (wc*32 + lcol)*128 + chunk*16;
  }

  auto STAGE = [&](const u16* Mat, int rbase, int isB, int h, int tt){
    const int rb = (tt < NT) ? ((tt & 1) * 65536 + isB * 32768 + h * 16384) : 131072;
    const int tc = (tt < NT) ? tt : NT - 1;
    #pragma unroll
    for (int s = 0; s < 2; ++s){
      const int o = (tid + s*512) << 4;
      const int row = o >> 7;
      const int c = (o >> 4) & 7;
      const char* src = (const char*)(Mat + (size_t)(rbase + h*128 + row) * K + (size_t)tc * 64)
                        + ((c ^ (row & 7)) << 4);
      gload_lds16(src, (char*)lds + rb + o);
    }
  };

  f32x4 acc[8][4] = {};
  bf16x8 af[4][2], bv[2][2];

  STAGE(A,  m0, 0, 0, 0);
  STAGE(Bt, n0, 1, 0, 0);
  STAGE(A,  m0, 0, 1, 0);
  STAGE(Bt, n0, 1, 1, 0);
  STAGE(A,  m0, 0, 0, 1);
  STAGE(Bt, n0, 1, 1, 1);
  STAGE(A,  m0, 0, 1, 1);
  asm volatile("s_waitcnt vmcnt(6)" ::: "memory");
  BAR();

  for (int i = 0; i < NI; ++i) {
    const int T = 2*i;
    ph256<0, 0, 0, 1, -1>(lds, aoff, boff, af, bv, acc, [&]{ STAGE(Bt, n0, 1, 0, T+1); });
    ph256<0, 1, 0, 0, -1>(lds, aoff, boff, af, bv, acc, [&]{ STAGE(A,  m0, 0, 0, T+2); });
    ph256<1, 1, 0, 1, -1>(lds, aoff, boff, af, bv, acc, [&]{});
    ph256<1, 0, 0, 0,  4>(lds, aoff, boff, af, bv, acc, [&]{ STAGE(Bt, n0, 1, 1, T+2); });
    ph256<0, 0, 1, 1, -1>(lds, aoff, boff, af, bv, acc, [&]{ STAGE(Bt, n0, 1, 0, T+2); });
    ph256<0, 1, 1, 0, -1>(lds, aoff, boff, af, bv, acc, [&]{ STAGE(A,  m0, 0, 1, T+2); });
    ph256<1, 1, 1, 1, -1>(lds, aoff, boff, af, bv, acc, [&]{ STAGE(A,  m0, 0, 0, T+3); });
    ph256<1, 0, 1, 0,  6>(lds, aoff, boff, af, bv, acc, [&]{ STAGE(Bt, n0, 1, 1, T+3); STAGE(A, m0, 0, 1, T+3); });
  }

  { size_t bp = (size_t)bias, ap = (size_t)add;
    asm volatile("" : "+v"(bp), "+v"(ap));
    bias = (const float*)bp; add = (const float*)ap; }

  #pragma unroll
  for (int mi = 0; mi < 8; ++mi) {
    const int gmb = m0 + (mi>>2)*128 + wr*64 + (mi&3)*16 + lrow4*4;
    #pragma unroll
    for (int ni = 0; ni < 4; ++ni) {
      const int gn = n0 + (ni>>1)*128 + wc*32 + (ni&1)*16 + lcol;
      const float bs = bias[gn];
      #pragma unroll
      for (int rr = 0; rr < 4; ++rr) {
        const int gm = gmb + rr;
        float v = acc[mi][ni][rr] + bs;
        if constexpr (EPI == 0) {
          const int which = gn >> 10, g = gn & 1023;
          const int b = gm >> 11, s = gm & 2047;
          const int h = g >> 6, d = g & 63;
          ((u16*)out)[(size_t)which * 8388608 + ((((size_t)((b << 4) + h) << 11) + s) << 6) + d] = f2bf(v);
        } else {
          ((u16*)out)[(size_t)gm * N + gn] = f2bf(0.5f * v * (1.f + erff(v * 0.70710678118f)));
        }
      }
    }
  }
}

// ================= 128x256 4-phase bf16 GEMM (wide) ====
// EPI 0: bf16 scatter to q/k/v (+bias); EPI 1: f32 = acc + bias + add
template<int QN, int LB, int RDA, int WAIT, typename F>
__device__ __forceinline__ void phW(const char* lds, const int (&aoff)[2], const int (&boff)[2],
    bf16x8 (&af)[4][2], bf16x8 (&bv)[2][2], f32x4 (&acc)[4][4], F&& stg){
  if constexpr (RDA) {
    const char* Ar = lds + LB*49152;
    #pragma unroll
    for (int fi = 0; fi < 4; ++fi)
      #pragma unroll
      for (int ks = 0; ks < 2; ++ks)
        af[fi][ks] = *(const bf16x8*)(Ar + fi*2048 + aoff[ks]);
  }
  {
    const char* Br = lds + LB*49152 + 16384 + QN*16384;
    #pragma unroll
    for (int fj = 0; fj < 2; ++fj)
      #pragma unroll
      for (int ks = 0; ks < 2; ++ks)
        bv[fj][ks] = *(const bf16x8*)(Br + fj*2048 + boff[ks]);
  }
  stg();
  BAR();
  asm volatile("s_waitcnt lgkmcnt(0)" ::: "memory");
  __builtin_amdgcn_sched_barrier(0);
  __builtin_amdgcn_s_setprio(1);
  #pragma unroll
  for (int fi = 0; fi < 4; ++fi)
    #pragma unroll
    for (int fj = 0; fj < 2; ++fj){
      acc[fi][QN*2+fj] = __builtin_amdgcn_mfma_f32_16x16x32_bf16(af[fi][0], bv[fj][0], acc[fi][QN*2+fj], 0, 0, 0);
      acc[fi][QN*2+fj] = __builtin_amdgcn_mfma_f32_16x16x32_bf16(af[fi][1], bv[fj][1], acc[fi][QN*2+fj], 0, 0, 0);
    }
  __builtin_amdgcn_s_setprio(0);
  if constexpr (WAIT >= 0)
    asm volatile("s_waitcnt vmcnt(%0)" :: "n"(WAIT) : "memory");
  BAR();
}

template<int EPI>
__global__ __launch_bounds__(512, 2) void gemmW(
    const u16* __restrict__ A, const u16* __restrict__ Bt,
    const float* __restrict__ bias, const float* __restrict__ add,
    void* __restrict__ out, int M, int N, int K)
{
  __shared__ char lds[106496];
  const int NT = K >> 6;
  const int NI = NT >> 1;
  const int nbx = N >> 8;
  const int nwg = gridDim.x, orig = blockIdx.x;
  const int q = nwg >> 3, r = nwg & 7, x = orig & 7;
  const int wg = (x < r ? x * (q + 1) : r * (q + 1) + (x - r) * q) + (orig >> 3);
  const int bx = wg % nbx, by = wg / nbx;
  const int m0 = by << 7, n0 = bx << 8;

  const int tid = threadIdx.x, wave = tid >> 6, lane = tid & 63;
  const int wr = wave >> 2, wc = wave & 3;
  const int lcol = lane & 15, lrow4 = lane >> 4;

  int aoff[2], boff[2];
  #pragma unroll
  for (int ks = 0; ks < 2; ++ks){
    const int chunk = (ks*4 + lrow4) ^ (lane & 7);
    aoff[ks] = (wr*64 + lcol)*128 + chunk*16;
    boff[ks] = (wc*32 + lcol)*128 + chunk*16;
  }

  auto STAGE = [&](const u16* Mat, int rbase, int kind, int tt){
    const int rb = (tt < NT) ? ((tt & 1) * 49152 + kind * 16384) : 98304;
    const int tc = (tt < NT) ? tt : NT - 1;
    #pragma unroll
    for (int s = 0; s < 2; ++s){
      const int o = (tid + s*512) << 4;
      const int row = o >> 7;
      const int c = (o >> 4) & 7;
      const char* src = (const char*)(Mat + (size_t)(rbase + row) * K + (size_t)tc * 64)
                        + ((c ^ (row & 7)) << 4);
      gload_lds16(src, (char*)lds + rb + o);
    }
  };

  f32x4 acc[4][4] = {};
  bf16x8 af[4][2], bv[2][2];

  STAGE(A,  m0,       0, 0);
  STAGE(Bt, n0,       1, 0);
  STAGE(Bt, n0 + 128, 2, 0);
  STAGE(A,  m0,       0, 1);
  STAGE(Bt, n0,       1, 1);
  asm volatile("s_waitcnt vmcnt(4)" ::: "memory");
  BAR();

  for (int i = 0; i < NI; ++i) {
    const int T = 2*i;
    phW<0, 0, 1, -1>(lds, aoff, boff, af, bv, acc, [&]{ STAGE(Bt, n0 + 128, 2, T+1); });
    phW<1, 0, 0,  4>(lds, aoff, boff, af, bv, acc, [&]{ STAGE(A, m0, 0, T+2); STAGE(Bt, n0, 1, T+2); });
    phW<0, 1, 1, -1>(lds, aoff, boff, af, bv, acc, [&]{ STAGE(Bt, n0 + 128, 2, T+2); });
    phW<1, 1, 0,  4>(lds, aoff, boff, af, bv, acc, [&]{ STAGE(A, m0, 0, T+3); STAGE(Bt, n0, 1, T+3); });
  }

  { size_t bp = (size_t)bias, ap = (size_t)add;
    asm volatile("" : "+v"(bp), "+v"(ap));
    bias = (const float*)bp; add = (const float*)ap; }

  #pragma unroll
  for (int fi = 0; fi < 4; ++fi) {
    const int gmb = m0 + wr*64 + fi*16 + lrow4*4;
    #pragma unroll
    for (int j = 0; j < 4; ++j) {
      const int gn = n0 + (j>>1)*128 + wc*32 + (j&1)*16 + lcol;
      const float bs = bias[gn];
      #pragma unroll
      for (int rr = 0; rr < 4; ++rr) {
        const int gm = gmb + rr;
        float v = acc[fi][j][rr] + bs;
        if constexpr (EPI == 0) {
          const int which = gn >> 10, g = gn & 1023;
          const int b = gm >> 11, s = gm & 2047;
          const int h = g >> 6, d = g & 63;
          ((u16*)out)[(size_t)which * 8388608 + ((((size_t)((b << 4) + h) << 11) + s) << 6) + d] = f2bf(v);
        } else {
          ((float*)out)[(size_t)gm * N + gn] = v + add[(size_t)gm * N + gn];
        }
      }
    }
  }
}

// ================= windowed attention: r12 optimum (half-split online softmax,
// 512 blocks x 256 thr, (256,1) -> VGPR 236 no-spill, LDS = V^T 64KB, single
// launch, parity buffers + merge). Measured: 140 us, FETCH 26MB, WRITE 31MB.
template<int NJ>  // NJ = W/16 (24 or 32)
__device__ void attn_core(const u16* __restrict__ Qp, const u16* __restrict__ Kp,
    u16* __restrict__ ctxP, const char* vtb, int start, int widx, int bh)
{
  const int tid = threadIdx.x, wave = tid >> 6, lane = tid & 63;
  const int q = lane & 15, g = lane >> 4;
  constexpr int HALF = NJ / 2;
  const float scale = 0.125f;  // 64^-0.5
  const int b = bh >> 4, h = bh & 15;

  for (int qt = wave; qt < NJ; qt += 4) {
    const int q0 = qt * 16;
    const bf16x8 bq0 = *(const bf16x8*)(Qp + (q0 + q) * 64 + g * 8);
    const bf16x8 bq1 = *(const bf16x8*)(Qp + (q0 + q) * 64 + 32 + g * 8);
    float m = -3.0e38f, l = 0.f;
    f32x4 o[4] = {};
    const int s0 = ((g & 1) << 5) + q;
    const int s1 = s0 + 16;
    const bool lowj = (g < 2);

    #pragma unroll
    for (int hh = 0; hh < 2; ++hh) {
      f32x4 acc[HALF];
      #pragma unroll
      for (int j = 0; j < HALF; ++j) {
        const int jj = hh * HALF + j;
        bf16x8 k0 = *(const bf16x8*)(Kp + (jj*16 + q) * 64 + g * 8);
        bf16x8 k1 = *(const bf16x8*)(Kp + (jj*16 + q) * 64 + 32 + g * 8);
        f32x4 t = {};
        t = __builtin_amdgcn_mfma_f32_16x16x32_bf16(k0, bq0, t, 0, 0, 0);
        t = __builtin_amdgcn_mfma_f32_16x16x32_bf16(k1, bq1, t, 0, 0, 0);
        acc[j] = t;
        if ((j & 3) == 3) __builtin_amdgcn_sched_barrier(0);  // cap load hoisting
      }
      float mh = -3.0e38f;
      #pragma unroll
      for (int j = 0; j < HALF; ++j)
        #pragma unroll
        for (int r = 0; r < 4; ++r) mh = fmaxf(mh, acc[j][r]);
      mh = fmaxf(mh, __shfl_xor(mh, 16, 64));
      mh = fmaxf(mh, __shfl_xor(mh, 32, 64));
      const float mn = fmaxf(m, mh);
      const float fr = __expf((m - mn) * scale);
      m = mn;
      l *= fr;
      #pragma unroll
      for (int df = 0; df < 4; ++df)
        #pragma unroll
        for (int r = 0; r < 4; ++r) o[df][r] *= fr;
      #pragma unroll
      for (int j = 0; j < HALF; ++j)
        #pragma unroll
        for (int r = 0; r < 4; ++r) {
          float e = __expf((acc[j][r] - mn) * scale);
          acc[j][r] = e;
          l += e;
        }
      #pragma unroll
      for (int c = 0; c < HALF / 2; ++c) {
        const u32 a0 = pack2(acc[2*c][0],   acc[2*c][1]);
        const u32 b0 = pack2(acc[2*c][2],   acc[2*c][3]);
        const u32 a1 = pack2(acc[2*c+1][0], acc[2*c+1][1]);
        const u32 b1 = pack2(acc[2*c+1][2], acc[2*c+1][3]);
        const u32 A0l = __shfl(a0, s0, 64), A1l = __shfl(a1, s0, 64);
        const u32 B0l = __shfl(b0, s0, 64), B1l = __shfl(b1, s0, 64);
        const u32 A0h = __shfl(a0, s1, 64), A1h = __shfl(a1, s1, 64);
        const u32 B0h = __shfl(b0, s1, 64), B1h = __shfl(b1, s1, 64);
        union { u32 u[4]; bf16x8 v; } pf;
        pf.u[0] = lowj ? A0l : A1l;
        pf.u[1] = lowj ? B0l : B1l;
        pf.u[2] = lowj ? A0h : A1h;
        pf.u[3] = lowj ? B0h : B1h;
        const int cg = hh * (HALF / 2) + c;
        #pragma unroll
        for (int df = 0; df < 4; ++df) {
          bf16x8 pv = *(const bf16x8*)(vtb + swz(df*16 + q, (cg*32 + g*8) * 2));
          o[df] = __builtin_amdgcn_mfma_f32_16x16x32_bf16(pv, pf.v, o[df], 0, 0, 0);
        }
        if ((c & 1) == 1) __builtin_amdgcn_sched_barrier(0);
      }
    }
    l += __shfl_xor(l, 16, 64);
    l += __shfl_xor(l, 32, 64);
    const float rs = 1.f / l;

    const int p = start + q0 + q;
    const int rel = p - (widx * 256 - 128);
    const float wgt = (rel < 256) ? ((widx == 0) ? 1.f : (float)rel * (1.f / 255.f))
                                  : ((widx == 7) ? 1.f : (1.f - (float)(rel - 256) * (1.f / 255.f)));
    const float rw = rs * wgt;
    u32 w0[4], w1[4];
    #pragma unroll
    for (int df = 0; df < 4; ++df) {
      w0[df] = pack2(o[df][0] * rw, o[df][1] * rw);
      w1[df] = pack2(o[df][2] * rw, o[df][3] * rw);
    }
    u32 W8[8] = {};
    #pragma unroll
    for (int df = 0; df < 4; ++df)
      #pragma unroll
      for (int sg = 0; sg < 4; ++sg) {
        const u32 t0 = __shfl(w0[df], sg*16 + q, 64);
        const u32 t1 = __shfl(w1[df], sg*16 + q, 64);
        if (g == df) { W8[2*sg] = t0; W8[2*sg+1] = t1; }
      }
    u16* dst = ctxP + ((((size_t)(b << 11) + (size_t)p) << 10) + (h << 6) + (g << 4));
    u32x4 lo = { W8[0], W8[1], W8[2], W8[3] };
    u32x4 hi = { W8[4], W8[5], W8[6], W8[7] };
    *(u32x4*)dst = lo;
    *(u32x4*)(dst + 8) = hi;
  }
}

__global__ __launch_bounds__(256, 1) void attn_kernel(const u16* __restrict__ qg, const u16* __restrict__ kg,
    const u16* __restrict__ vg, u16* __restrict__ ctxE, u16* __restrict__ ctxO){
  __shared__ u16 Vt[32768];   // V^T only: 64KB -> 2 blocks/CU
  const int widx = (int)blockIdx.x >> 6;
  const int bh = blockIdx.x & 63;
  const int i0 = widx << 8;
  int start = i0 - 128; if (start < 0) start = 0;
  int end = i0 + 384;   if (end > 2048) end = 2048;
  const int W = end - start;
  const int tid = threadIdx.x;
  const u16* Qp = qg + (((size_t)bh << 11) + start) * 64;
  const u16* Kp = kg + (((size_t)bh << 11) + start) * 64;
  const u16* Vp = vg + (((size_t)bh << 11) + start) * 64;
  char* vtb = (char*)Vt;
  for (int c = tid; c < W * 8; c += 256) {
    int key = c >> 3, d0 = (c & 7) << 3;
    u16x8 vv = *(const u16x8*)(Vp + key * 64 + d0);
    #pragma unroll
    for (int z = 0; z < 8; ++z)
      *(u16*)(vtb + swz(d0 + z, key * 2)) = vv[z];
  }
  __syncthreads();
  u16* ctxP = (widx & 1) ? ctxO : ctxE;
  if (W == 512) attn_core<32>(Qp, Kp, ctxP, vtb, start, widx, bh);
  else          attn_core<24>(Qp, Kp, ctxP, vtb, start, widx, bh);
}

// merge parity buffers: p<128 -> E; p>=1920 -> O; else E+O. In-place on E is safe.
__global__ __launch_bounds__(256) void merge_kernel(const u16* __restrict__ e,
    const u16* __restrict__ o, u16* __restrict__ out){
  const int i = blockIdx.x * 256 + threadIdx.x;     // u16x8 index
  const int p = (i >> 7) & 2047;                    // (i*8 >> 10) & 2047
  u16x8 ev = ((const u16x8*)e)[i];
  u16x8 ov = ((const u16x8*)o)[i];
  u16x8 r;
  if (p < 128)        r = ev;
  else if (p >= 1920) r = ov;
  else {
    #pragma unroll
    for (int z = 0; z < 8; ++z) r[z] = f2bf(bf2f(ev[z]) + bf2f(ov[z]));
  }
  ((u16x8*)out)[i] = r;
}

// ---------------- host
extern "C" void kernel_launch(void* const* d_in, const int* in_sizes, int n_in,
                              void* d_out, int out_size, void* d_ws, size_t ws_size,
                              hipStream_t stream) {
  const float* hidden = (const float*)d_in[0];
  const float* ln1_g  = (const float*)d_in[1];
  const float* ln1_b  = (const float*)d_in[2];
  const float* wq     = (const float*)d_in[3];
  const float* bq     = (const float*)d_in[4];
  const float* wk     = (const float*)d_in[5];
  const float* bk     = (const float*)d_in[6];
  const float* wv     = (const float*)d_in[7];
  const float* bv     = (const float*)d_in[8];
  const float* wproj  = (const float*)d_in[9];
  const float* bproj  = (const float*)d_in[10];
  const float* ln2_g  = (const float*)d_in[11];
  const float* ln2_b  = (const float*)d_in[12];
  const float* w1     = (const float*)d_in[13];
  const float* b1     = (const float*)d_in[14];
  const float* w2     = (const float*)d_in[15];
  const float* b2     = (const float*)d_in[16];

  char* ws = (char*)d_ws;
  u16* xb    = (u16*)(ws + 0);            // 16 MiB (LN1/LN2 out; ctxO during attn)
  u16* wqkvT = (u16*)(ws + 16777216);     // 6 MiB [3072][1024]
  u16* wpT   = (u16*)(ws + 23068672);     // 2 MiB
  u16* w1T   = (u16*)(ws + 25165824);     // 8 MiB
  u16* w2T   = (u16*)(ws + 33554432);     // 8 MiB
  u16* qb    = (u16*)(ws + 41943040);     // q,k,v contiguous: 3 x 16 MiB
  u16* kb    = (u16*)(ws + 58720256);
  u16* vb    = (u16*)(ws + 75497472);
  u16* ctxE  = (u16*)(ws + 92274688);     // 16 MiB (merged ctx in-place)
  u16* ctxO  = (u16*)(ws + 0);            // aliases xb (dead between qkv and ln2)
  float* bqkv = (float*)(ws + 92274688);  // aliases ctxE start (dead before attn)
  float* res2 = (float*)(ws + 109051904); // 32 MiB f32
  u16* mid   = (u16*)(ws + 41943040);     // 64 MiB, reuses qb..ctx

  dim3 tb(32, 8);
  transpose_cvt<<<dim3(32, 32), tb, 0, stream>>>(wq, wqkvT, 1024, 1024);
  transpose_cvt<<<dim3(32, 32), tb, 0, stream>>>(wk, wqkvT + 1048576, 1024, 1024);
  transpose_cvt<<<dim3(32, 32), tb, 0, stream>>>(wv, wqkvT + 2097152, 1024, 1024);
  transpose_cvt<<<dim3(32, 32), tb, 0, stream>>>(wproj, wpT, 1024, 1024);
  transpose_cvt<<<dim3(128, 32), tb, 0, stream>>>(w1, w1T, 1024, 4096);
  transpose_cvt<<<dim3(32, 128), tb, 0, stream>>>(w2, w2T, 4096, 1024);
  concat3<<<12, 256, 0, stream>>>(bq, bk, bv, bqkv);

  ln_kernel<<<8192, 256, 0, stream>>>(hidden, ln1_g, ln1_b, xb);

  // qkv via wide tile: 64 x 12 = 768 blocks = 3 exact passes on 256 CUs
  gemmW<0><<<768, 512, 0, stream>>>(xb, wqkvT, bqkv, nullptr, qb, 8192, 3072, 1024);

  attn_kernel<<<512, 256, 0, stream>>>(qb, kb, vb, ctxE, ctxO);
  merge_kernel<<<4096, 256, 0, stream>>>(ctxE, ctxO, ctxE);

  gemmW<1><<<256, 512, 0, stream>>>(ctxE, wpT, bproj, hidden, res2, 8192, 1024, 1024);

  ln_kernel<<<8192, 256, 0, stream>>>(res2, ln2_g, ln2_b, xb);

  gemm8<2><<<512, 512, 0, stream>>>(xb, w1T, b1, nullptr, mid, 8192, 4096, 1024);
  gemmW<1><<<256, 512, 0, stream>>>(mid, w2T, b2, res2, (float*)d_out, 8192, 1024, 4096);
}

// Round 16
// 426.157 us; speedup vs baseline: 1.1238x; 1.0915x over previous
//
#include <hip/hip_runtime.h>
#include <math.h>

typedef unsigned short u16;
typedef unsigned int u32;
typedef __attribute__((ext_vector_type(8))) short bf16x8;
typedef __attribute__((ext_vector_type(8))) unsigned short u16x8;
typedef __attribute__((ext_vector_type(4))) float f32x4;
typedef __attribute__((ext_vector_type(4))) unsigned int u32x4;

__device__ __forceinline__ u16 f2bf(float f){
  union { float f; unsigned u; } c; c.f = f;
  unsigned u = c.u;
  return (u16)((u + 0x7fffu + ((u >> 16) & 1u)) >> 16);
}
__device__ __forceinline__ float bf2f(u16 h){
  union { unsigned u; float f; } c; c.u = ((unsigned)h) << 16;
  return c.f;
}
__device__ __forceinline__ u32 pack2(float lo, float hi){
  return (u32)f2bf(lo) | ((u32)f2bf(hi) << 16);
}
__device__ __forceinline__ void gload_lds16(const void* g, void* l){
  __builtin_amdgcn_global_load_lds((const __attribute__((address_space(1))) void*)g,
                                   (__attribute__((address_space(3))) void*)l, 16, 0, 0);
}
// XOR swizzle within a 1024B LDS row (attention V^T)
__device__ __forceinline__ int swz(int row, int bc){
  return (row << 10) + (bc ^ ((row & 7) << 4));
}

#define BAR() asm volatile("s_barrier" ::: "memory")

// ---------------- weight transpose + f32->bf16 : in [K][N] f32 -> out [N][K] bf16
__global__ void transpose_cvt(const float* __restrict__ in, u16* __restrict__ out, int K, int N){
  __shared__ float tile[32][33];
  int n0 = blockIdx.x << 5, k0 = blockIdx.y << 5;
  int tx = threadIdx.x, ty = threadIdx.y;
  #pragma unroll
  for (int r = 0; r < 32; r += 8)
    tile[ty + r][tx] = in[(size_t)(k0 + ty + r) * N + n0 + tx];
  __syncthreads();
  #pragma unroll
  for (int r = 0; r < 32; r += 8)
    out[(size_t)(n0 + ty + r) * K + k0 + tx] = f2bf(tile[tx][ty + r]);
}

__global__ void concat3(const float* __restrict__ a, const float* __restrict__ b,
                        const float* __restrict__ c, float* __restrict__ o){
  int i = blockIdx.x * 256 + threadIdx.x;
  o[i] = i < 1024 ? a[i] : (i < 2048 ? b[i - 1024] : c[i - 2048]);
}

// ---------------- layernorm: [rows][1024] (f32 or bf16 in) -> bf16 out
__device__ __forceinline__ float blockReduce(float v, float* ws){
  #pragma unroll
  for (int m = 1; m < 64; m <<= 1) v += __shfl_xor(v, m, 64);
  int w = threadIdx.x >> 6;
  __syncthreads();
  if ((threadIdx.x & 63) == 0) ws[w] = v;
  __syncthreads();
  return ws[0] + ws[1] + ws[2] + ws[3];
}

struct U16x4 { u16 x, y, z, w; };

template<int BF16IN>
__global__ __launch_bounds__(256) void ln_kernel(const void* __restrict__ in_, const float* __restrict__ g,
    const float* __restrict__ be, u16* __restrict__ out){
  __shared__ float ws[4];
  int row = blockIdx.x;
  float vx, vy, vz, vw;
  if constexpr (BF16IN) {
    const U16x4 v = ((const U16x4*)((const u16*)in_ + ((size_t)row << 10)))[threadIdx.x];
    vx = bf2f(v.x); vy = bf2f(v.y); vz = bf2f(v.z); vw = bf2f(v.w);
  } else {
    const float4 v = ((const float4*)((const float*)in_ + ((size_t)row << 10)))[threadIdx.x];
    vx = v.x; vy = v.y; vz = v.z; vw = v.w;
  }
  float s = vx + vy + vz + vw;
  s = blockReduce(s, ws);
  float mean = s * (1.f / 1024.f);
  float dx = vx - mean, dy = vy - mean, dz = vz - mean, dw = vw - mean;
  float s2 = dx*dx + dy*dy + dz*dz + dw*dw;
  s2 = blockReduce(s2, ws);
  float rstd = rsqrtf(s2 * (1.f / 1024.f) + 1e-5f);
  float4 gv = ((const float4*)g)[threadIdx.x];
  float4 bv = ((const float4*)be)[threadIdx.x];
  U16x4 ov;
  ov.x = f2bf(dx * rstd * gv.x + bv.x);
  ov.y = f2bf(dy * rstd * gv.y + bv.y);
  ov.z = f2bf(dz * rstd * gv.z + bv.z);
  ov.w = f2bf(dw * rstd * gv.w + bv.w);
  ((U16x4*)(out + ((size_t)row << 10)))[threadIdx.x] = ov;
}

// ================= 256x256 8-phase bf16 GEMM =========
template<int QM, int QN, int LB, int RDA, int WAIT, typename F>
__device__ __forceinline__ void ph256(const char* lds, const int (&aoff)[2], const int (&boff)[2],
    bf16x8 (&af)[4][2], bf16x8 (&bv)[2][2], f32x4 (&acc)[8][4], F&& stg){
  if constexpr (RDA) {
    const char* Ar = lds + LB*65536 + QM*16384;
    #pragma unroll
    for (int fi = 0; fi < 4; ++fi)
      #pragma unroll
      for (int ks = 0; ks < 2; ++ks)
        af[fi][ks] = *(const bf16x8*)(Ar + fi*2048 + aoff[ks]);
  }
  {
    const char* Br = lds + LB*65536 + 32768 + QN*16384;
    #pragma unroll
    for (int fj = 0; fj < 2; ++fj)
      #pragma unroll
      for (int ks = 0; ks < 2; ++ks)
        bv[fj][ks] = *(const bf16x8*)(Br + fj*2048 + boff[ks]);
  }
  stg();
  BAR();
  asm volatile("s_waitcnt lgkmcnt(0)" ::: "memory");
  __builtin_amdgcn_sched_barrier(0);
  __builtin_amdgcn_s_setprio(1);
  #pragma unroll
  for (int fi = 0; fi < 4; ++fi)
    #pragma unroll
    for (int fj = 0; fj < 2; ++fj){
      acc[QM*4+fi][QN*2+fj] = __builtin_amdgcn_mfma_f32_16x16x32_bf16(af[fi][0], bv[fj][0], acc[QM*4+fi][QN*2+fj], 0, 0, 0);
      acc[QM*4+fi][QN*2+fj] = __builtin_amdgcn_mfma_f32_16x16x32_bf16(af[fi][1], bv[fj][1], acc[QM*4+fi][QN*2+fj], 0, 0, 0);
    }
  __builtin_amdgcn_s_setprio(0);
  if constexpr (WAIT >= 0)
    asm volatile("s_waitcnt vmcnt(%0)" :: "n"(WAIT) : "memory");
  BAR();
}

// EPI 0: bf16 scatter to q/k/v [3][B*NH, S, HD] (+bias)
// EPI 2: bf16 = gelu(acc + bias)   [tanh-form sigmoid approx, overflow-safe]
template<int EPI>
__global__ __launch_bounds__(512, 2) void gemm8(
    const u16* __restrict__ A, const u16* __restrict__ Bt,
    const float* __restrict__ bias, const float* __restrict__ add,
    void* __restrict__ out, int M, int N, int K)
{
  __shared__ char lds[147456];
  const int NT = K >> 6;
  const int NI = NT >> 1;
  const int nbx = N >> 8;
  const int nwg = gridDim.x, orig = blockIdx.x;
  const int q = nwg >> 3, r = nwg & 7, x = orig & 7;
  const int wg = (x < r ? x * (q + 1) : r * (q + 1) + (x - r) * q) + (orig >> 3);
  const int bx = wg % nbx, by = wg / nbx;
  const int m0 = by << 8, n0 = bx << 8;

  const int tid = threadIdx.x, wave = tid >> 6, lane = tid & 63;
  const int wr = (wave >> 2) & 1, wc = wave & 3;
  const int lcol = lane & 15, lrow4 = lane >> 4;

  int aoff[2], boff[2];
  #pragma unroll
  for (int ks = 0; ks < 2; ++ks){
    const int chunk = (ks*4 + lrow4) ^ (lane & 7);
    aoff[ks] = (wr*64 + lcol)*128 + chunk*16;
    boff[ks] = (wc*32 + lcol)*128 + chunk*16;
  }

  auto STAGE = [&](const u16* Mat, int rbase, int isB, int h, int tt){
    const int rb = (tt < NT) ? ((tt & 1) * 65536 + isB * 32768 + h * 16384) : 131072;
    const int tc = (tt < NT) ? tt : NT - 1;
    #pragma unroll
    for (int s = 0; s < 2; ++s){
      const int o = (tid + s*512) << 4;
      const int row = o >> 7;
      const int c = (o >> 4) & 7;
      const char* src = (const char*)(Mat + (size_t)(rbase + h*128 + row) * K + (size_t)tc * 64)
                        + ((c ^ (row & 7)) << 4);
      gload_lds16(src, (char*)lds + rb + o);
    }
  };

  f32x4 acc[8][4] = {};
  bf16x8 af[4][2], bv[2][2];

  STAGE(A,  m0, 0, 0, 0);
  STAGE(Bt, n0, 1, 0, 0);
  STAGE(A,  m0, 0, 1, 0);
  STAGE(Bt, n0, 1, 1, 0);
  STAGE(A,  m0, 0, 0, 1);
  STAGE(Bt, n0, 1, 1, 1);
  STAGE(A,  m0, 0, 1, 1);
  asm volatile("s_waitcnt vmcnt(6)" ::: "memory");
  BAR();

  for (int i = 0; i < NI; ++i) {
    const int T = 2*i;
    ph256<0, 0, 0, 1, -1>(lds, aoff, boff, af, bv, acc, [&]{ STAGE(Bt, n0, 1, 0, T+1); });
    ph256<0, 1, 0, 0, -1>(lds, aoff, boff, af, bv, acc, [&]{ STAGE(A,  m0, 0, 0, T+2); });
    ph256<1, 1, 0, 1, -1>(lds, aoff, boff, af, bv, acc, [&]{});
    ph256<1, 0, 0, 0,  4>(lds, aoff, boff, af, bv, acc, [&]{ STAGE(Bt, n0, 1, 1, T+2); });
    ph256<0, 0, 1, 1, -1>(lds, aoff, boff, af, bv, acc, [&]{ STAGE(Bt, n0, 1, 0, T+2); });
    ph256<0, 1, 1, 0, -1>(lds, aoff, boff, af, bv, acc, [&]{ STAGE(A,  m0, 0, 1, T+2); });
    ph256<1, 1, 1, 1, -1>(lds, aoff, boff, af, bv, acc, [&]{ STAGE(A,  m0, 0, 0, T+3); });
    ph256<1, 0, 1, 0,  6>(lds, aoff, boff, af, bv, acc, [&]{ STAGE(Bt, n0, 1, 1, T+3); STAGE(A, m0, 0, 1, T+3); });
  }

  { size_t bp = (size_t)bias, ap = (size_t)add;
    asm volatile("" : "+v"(bp), "+v"(ap));
    bias = (const float*)bp; add = (const float*)ap; }

  #pragma unroll
  for (int mi = 0; mi < 8; ++mi) {
    const int gmb = m0 + (mi>>2)*128 + wr*64 + (mi&3)*16 + lrow4*4;
    #pragma unroll
    for (int ni = 0; ni < 4; ++ni) {
      const int gn = n0 + (ni>>1)*128 + wc*32 + (ni&1)*16 + lcol;
      const float bs = bias[gn];
      #pragma unroll
      for (int rr = 0; rr < 4; ++rr) {
        const int gm = gmb + rr;
        float v = acc[mi][ni][rr] + bs;
        if constexpr (EPI == 0) {
          const int which = gn >> 10, g = gn & 1023;
          const int b = gm >> 11, s = gm & 2047;
          const int h = g >> 6, d = g & 63;
          ((u16*)out)[(size_t)which * 8388608 + ((((size_t)((b << 4) + h) << 11) + s) << 6) + d] = f2bf(v);
        } else {
          // gelu(v) ~= v - v/(1+e^{2y}), 2y = 1.5957691*(v + 0.044715 v^3)
          const float y2 = 1.5957691216f * v + 0.0713548353f * v * v * v;
          const float e = __expf(y2);
          ((u16*)out)[(size_t)gm * N + gn] = f2bf(v - v / (1.f + e));
        }
      }
    }
  }
}

// ================= 128x256 4-phase bf16 GEMM (wide) ====
// EPI 1: proj  -> out bf16 = acc + bias + add(f32)
// EPI 3: ffn2  -> out f32  = acc + bias + add(bf16)
template<int QN, int LB, int RDA, int WAIT, typename F>
__device__ __forceinline__ void phW(const char* lds, const int (&aoff)[2], const int (&boff)[2],
    bf16x8 (&af)[4][2], bf16x8 (&bv)[2][2], f32x4 (&acc)[4][4], F&& stg){
  if constexpr (RDA) {
    const char* Ar = lds + LB*49152;
    #pragma unroll
    for (int fi = 0; fi < 4; ++fi)
      #pragma unroll
      for (int ks = 0; ks < 2; ++ks)
        af[fi][ks] = *(const bf16x8*)(Ar + fi*2048 + aoff[ks]);
  }
  {
    const char* Br = lds + LB*49152 + 16384 + QN*16384;
    #pragma unroll
    for (int fj = 0; fj < 2; ++fj)
      #pragma unroll
      for (int ks = 0; ks < 2; ++ks)
        bv[fj][ks] = *(const bf16x8*)(Br + fj*2048 + boff[ks]);
  }
  stg();
  BAR();
  asm volatile("s_waitcnt lgkmcnt(0)" ::: "memory");
  __builtin_amdgcn_sched_barrier(0);
  __builtin_amdgcn_s_setprio(1);
  #pragma unroll
  for (int fi = 0; fi < 4; ++fi)
    #pragma unroll
    for (int fj = 0; fj < 2; ++fj){
      acc[fi][QN*2+fj] = __builtin_amdgcn_mfma_f32_16x16x32_bf16(af[fi][0], bv[fj][0], acc[fi][QN*2+fj], 0, 0, 0);
      acc[fi][QN*2+fj] = __builtin_amdgcn_mfma_f32_16x16x32_bf16(af[fi][1], bv[fj][1], acc[fi][QN*2+fj], 0, 0, 0);
    }
  __builtin_amdgcn_s_setprio(0);
  if constexpr (WAIT >= 0)
    asm volatile("s_waitcnt vmcnt(%0)" :: "n"(WAIT) : "memory");
  BAR();
}

template<int EPI>
__global__ __launch_bounds__(512, 2) void gemmW(
    const u16* __restrict__ A, const u16* __restrict__ Bt,
    const float* __restrict__ bias, const void* __restrict__ add,
    void* __restrict__ out, int M, int N, int K)
{
  __shared__ char lds[106496];
  const int NT = K >> 6;
  const int NI = NT >> 1;
  const int nbx = N >> 8;
  const int nwg = gridDim.x, orig = blockIdx.x;
  const int q = nwg >> 3, r = nwg & 7, x = orig & 7;
  const int wg = (x < r ? x * (q + 1) : r * (q + 1) + (x - r) * q) + (orig >> 3);
  const int bx = wg % nbx, by = wg / nbx;
  const int m0 = by << 7, n0 = bx << 8;

  const int tid = threadIdx.x, wave = tid >> 6, lane = tid & 63;
  const int wr = wave >> 2, wc = wave & 3;
  const int lcol = lane & 15, lrow4 = lane >> 4;

  int aoff[2], boff[2];
  #pragma unroll
  for (int ks = 0; ks < 2; ++ks){
    const int chunk = (ks*4 + lrow4) ^ (lane & 7);
    aoff[ks] = (wr*64 + lcol)*128 + chunk*16;
    boff[ks] = (wc*32 + lcol)*128 + chunk*16;
  }

  auto STAGE = [&](const u16* Mat, int rbase, int kind, int tt){
    const int rb = (tt < NT) ? ((tt & 1) * 49152 + kind * 16384) : 98304;
    const int tc = (tt < NT) ? tt : NT - 1;
    #pragma unroll
    for (int s = 0; s < 2; ++s){
      const int o = (tid + s*512) << 4;
      const int row = o >> 7;
      const int c = (o >> 4) & 7;
      const char* src = (const char*)(Mat + (size_t)(rbase + row) * K + (size_t)tc * 64)
                        + ((c ^ (row & 7)) << 4);
      gload_lds16(src, (char*)lds + rb + o);
    }
  };

  f32x4 acc[4][4] = {};
  bf16x8 af[4][2], bv[2][2];

  STAGE(A,  m0,       0, 0);
  STAGE(Bt, n0,       1, 0);
  STAGE(Bt, n0 + 128, 2, 0);
  STAGE(A,  m0,       0, 1);
  STAGE(Bt, n0,       1, 1);
  asm volatile("s_waitcnt vmcnt(4)" ::: "memory");
  BAR();

  for (int i = 0; i < NI; ++i) {
    const int T = 2*i;
    phW<0, 0, 1, -1>(lds, aoff, boff, af, bv, acc, [&]{ STAGE(Bt, n0 + 128, 2, T+1); });
    phW<1, 0, 0,  4>(lds, aoff, boff, af, bv, acc, [&]{ STAGE(A, m0, 0, T+2); STAGE(Bt, n0, 1, T+2); });
    phW<0, 1, 1, -1>(lds, aoff, boff, af, bv, acc, [&]{ STAGE(Bt, n0 + 128, 2, T+2); });
    phW<1, 1, 0,  4>(lds, aoff, boff, af, bv, acc, [&]{ STAGE(A, m0, 0, T+3); STAGE(Bt, n0, 1, T+3); });
  }

  { size_t bp = (size_t)bias, ap = (size_t)add;
    asm volatile("" : "+v"(bp), "+v"(ap));
    bias = (const float*)bp; add = (const void*)ap; }

  #pragma unroll
  for (int fi = 0; fi < 4; ++fi) {
    const int gmb = m0 + wr*64 + fi*16 + lrow4*4;
    #pragma unroll
    for (int j = 0; j < 4; ++j) {
      const int gn = n0 + (j>>1)*128 + wc*32 + (j&1)*16 + lcol;
      const float bs = bias[gn];
      #pragma unroll
      for (int rr = 0; rr < 4; ++rr) {
        const int gm = gmb + rr;
        float v = acc[fi][j][rr] + bs;
        if constexpr (EPI == 1) {
          ((u16*)out)[(size_t)gm * N + gn] = f2bf(v + ((const float*)add)[(size_t)gm * N + gn]);
        } else {
          ((float*)out)[(size_t)gm * N + gn] = v + bf2f(((const u16*)add)[(size_t)gm * N + gn]);
        }
      }
    }
  }
}

// ================= windowed attention: r12 optimum (half-split online softmax,
// 512 blocks x 256 thr, (256,1) -> VGPR 236 no-spill, LDS = V^T 64KB, single
// launch, parity buffers + merge). Measured: 140 us, FETCH 26MB, WRITE 31MB.
template<int NJ>  // NJ = W/16 (24 or 32)
__device__ void attn_core(const u16* __restrict__ Qp, const u16* __restrict__ Kp,
    u16* __restrict__ ctxP, const char* vtb, int start, int widx, int bh)
{
  const int tid = threadIdx.x, wave = tid >> 6, lane = tid & 63;
  const int q = lane & 15, g = lane >> 4;
  constexpr int HALF = NJ / 2;
  const float scale = 0.125f;  // 64^-0.5
  const int b = bh >> 4, h = bh & 15;

  for (int qt = wave; qt < NJ; qt += 4) {
    const int q0 = qt * 16;
    const bf16x8 bq0 = *(const bf16x8*)(Qp + (q0 + q) * 64 + g * 8);
    const bf16x8 bq1 = *(const bf16x8*)(Qp + (q0 + q) * 64 + 32 + g * 8);
    float m = -3.0e38f, l = 0.f;
    f32x4 o[4] = {};
    const int s0 = ((g & 1) << 5) + q;
    const int s1 = s0 + 16;
    const bool lowj = (g < 2);

    #pragma unroll
    for (int hh = 0; hh < 2; ++hh) {
      f32x4 acc[HALF];
      #pragma unroll
      for (int j = 0; j < HALF; ++j) {
        const int jj = hh * HALF + j;
        bf16x8 k0 = *(const bf16x8*)(Kp + (jj*16 + q) * 64 + g * 8);
        bf16x8 k1 = *(const bf16x8*)(Kp + (jj*16 + q) * 64 + 32 + g * 8);
        f32x4 t = {};
        t = __builtin_amdgcn_mfma_f32_16x16x32_bf16(k0, bq0, t, 0, 0, 0);
        t = __builtin_amdgcn_mfma_f32_16x16x32_bf16(k1, bq1, t, 0, 0, 0);
        acc[j] = t;
        if ((j & 3) == 3) __builtin_amdgcn_sched_barrier(0);  // cap load hoisting
      }
      float mh = -3.0e38f;
      #pragma unroll
      for (int j = 0; j < HALF; ++j)
        #pragma unroll
        for (int r = 0; r < 4; ++r) mh = fmaxf(mh, acc[j][r]);
      mh = fmaxf(mh, __shfl_xor(mh, 16, 64));
      mh = fmaxf(mh, __shfl_xor(mh, 32, 64));
      const float mn = fmaxf(m, mh);
      const float fr = __expf((m - mn) * scale);
      m = mn;
      l *= fr;
      #pragma unroll
      for (int df = 0; df < 4; ++df)
        #pragma unroll
        for (int r = 0; r < 4; ++r) o[df][r] *= fr;
      #pragma unroll
      for (int j = 0; j < HALF; ++j)
        #pragma unroll
        for (int r = 0; r < 4; ++r) {
          float e = __expf((acc[j][r] - mn) * scale);
          acc[j][r] = e;
          l += e;
        }
      #pragma unroll
      for (int c = 0; c < HALF / 2; ++c) {
        const u32 a0 = pack2(acc[2*c][0],   acc[2*c][1]);
        const u32 b0 = pack2(acc[2*c][2],   acc[2*c][3]);
        const u32 a1 = pack2(acc[2*c+1][0], acc[2*c+1][1]);
        const u32 b1 = pack2(acc[2*c+1][2], acc[2*c+1][3]);
        const u32 A0l = __shfl(a0, s0, 64), A1l = __shfl(a1, s0, 64);
        const u32 B0l = __shfl(b0, s0, 64), B1l = __shfl(b1, s0, 64);
        const u32 A0h = __shfl(a0, s1, 64), A1h = __shfl(a1, s1, 64);
        const u32 B0h = __shfl(b0, s1, 64), B1h = __shfl(b1, s1, 64);
        union { u32 u[4]; bf16x8 v; } pf;
        pf.u[0] = lowj ? A0l : A1l;
        pf.u[1] = lowj ? B0l : B1l;
        pf.u[2] = lowj ? A0h : A1h;
        pf.u[3] = lowj ? B0h : B1h;
        const int cg = hh * (HALF / 2) + c;
        #pragma unroll
        for (int df = 0; df < 4; ++df) {
          bf16x8 pv = *(const bf16x8*)(vtb + swz(df*16 + q, (cg*32 + g*8) * 2));
          o[df] = __builtin_amdgcn_mfma_f32_16x16x32_bf16(pv, pf.v, o[df], 0, 0, 0);
        }
        if ((c & 1) == 1) __builtin_amdgcn_sched_barrier(0);
      }
    }
    l += __shfl_xor(l, 16, 64);
    l += __shfl_xor(l, 32, 64);
    const float rs = 1.f / l;

    const int p = start + q0 + q;
    const int rel = p - (widx * 256 - 128);
    const float wgt = (rel < 256) ? ((widx == 0) ? 1.f : (float)rel * (1.f / 255.f))
                                  : ((widx == 7) ? 1.f : (1.f - (float)(rel - 256) * (1.f / 255.f)));
    const float rw = rs * wgt;
    u32 w0[4], w1[4];
    #pragma unroll
    for (int df = 0; df < 4; ++df) {
      w0[df] = pack2(o[df][0] * rw, o[df][1] * rw);
      w1[df] = pack2(o[df][2] * rw, o[df][3] * rw);
    }
    u32 W8[8] = {};
    #pragma unroll
    for (int df = 0; df < 4; ++df)
      #pragma unroll
      for (int sg = 0; sg < 4; ++sg) {
        const u32 t0 = __shfl(w0[df], sg*16 + q, 64);
        const u32 t1 = __shfl(w1[df], sg*16 + q, 64);
        if (g == df) { W8[2*sg] = t0; W8[2*sg+1] = t1; }
      }
    u16* dst = ctxP + ((((size_t)(b << 11) + (size_t)p) << 10) + (h << 6) + (g << 4));
    u32x4 lo = { W8[0], W8[1], W8[2], W8[3] };
    u32x4 hi = { W8[4], W8[5], W8[6], W8[7] };
    *(u32x4*)dst = lo;
    *(u32x4*)(dst + 8) = hi;
  }
}

__global__ __launch_bounds__(256, 1) void attn_kernel(const u16* __restrict__ qg, const u16* __restrict__ kg,
    const u16* __restrict__ vg, u16* __restrict__ ctxE, u16* __restrict__ ctxO){
  __shared__ u16 Vt[32768];   // V^T only: 64KB -> 2 blocks/CU
  const int widx = (int)blockIdx.x >> 6;
  const int bh = blockIdx.x & 63;
  const int i0 = widx << 8;
  int start = i0 - 128; if (start < 0) start = 0;
  int end = i0 + 384;   if (end > 2048) end = 2048;
  const int W = end - start;
  const int tid = threadIdx.x;
  const u16* Qp = qg + (((size_t)bh << 11) + start) * 64;
  const u16* Kp = kg + (((size_t)bh << 11) + start) * 64;
  const u16* Vp = vg + (((size_t)bh << 11) + start) * 64;
  char* vtb = (char*)Vt;
  for (int c = tid; c < W * 8; c += 256) {
    int key = c >> 3, d0 = (c & 7) << 3;
    u16x8 vv = *(const u16x8*)(Vp + key * 64 + d0);
    #pragma unroll
    for (int z = 0; z < 8; ++z)
      *(u16*)(vtb + swz(d0 + z, key * 2)) = vv[z];
  }
  __syncthreads();
  u16* ctxP = (widx & 1) ? ctxO : ctxE;
  if (W == 512) attn_core<32>(Qp, Kp, ctxP, vtb, start, widx, bh);
  else          attn_core<24>(Qp, Kp, ctxP, vtb, start, widx, bh);
}

// merge parity buffers: p<128 -> E; p>=1920 -> O; else E+O. In-place on E is safe.
__global__ __launch_bounds__(256) void merge_kernel(const u16* __restrict__ e,
    const u16* __restrict__ o, u16* __restrict__ out){
  const int i = blockIdx.x * 256 + threadIdx.x;     // u16x8 index
  const int p = (i >> 7) & 2047;                    // (i*8 >> 10) & 2047
  u16x8 ev = ((const u16x8*)e)[i];
  u16x8 ov = ((const u16x8*)o)[i];
  u16x8 r;
  if (p < 128)        r = ev;
  else if (p >= 1920) r = ov;
  else {
    #pragma unroll
    for (int z = 0; z < 8; ++z) r[z] = f2bf(bf2f(ev[z]) + bf2f(ov[z]));
  }
  ((u16x8*)out)[i] = r;
}

// ---------------- host
extern "C" void kernel_launch(void* const* d_in, const int* in_sizes, int n_in,
                              void* d_out, int out_size, void* d_ws, size_t ws_size,
                              hipStream_t stream) {
  const float* hidden = (const float*)d_in[0];
  const float* ln1_g  = (const float*)d_in[1];
  const float* ln1_b  = (const float*)d_in[2];
  const float* wq     = (const float*)d_in[3];
  const float* bq     = (const float*)d_in[4];
  const float* wk     = (const float*)d_in[5];
  const float* bk     = (const float*)d_in[6];
  const float* wv     = (const float*)d_in[7];
  const float* bv     = (const float*)d_in[8];
  const float* wproj  = (const float*)d_in[9];
  const float* bproj  = (const float*)d_in[10];
  const float* ln2_g  = (const float*)d_in[11];
  const float* ln2_b  = (const float*)d_in[12];
  const float* w1     = (const float*)d_in[13];
  const float* b1     = (const float*)d_in[14];
  const float* w2     = (const float*)d_in[15];
  const float* b2     = (const float*)d_in[16];

  char* ws = (char*)d_ws;
  u16* xb    = (u16*)(ws + 0);            // 16 MiB (LN1/LN2 out; ctxO during attn)
  u16* wqkvT = (u16*)(ws + 16777216);     // 6 MiB [3072][1024]
  u16* wpT   = (u16*)(ws + 23068672);     // 2 MiB
  u16* w1T   = (u16*)(ws + 25165824);     // 8 MiB
  u16* w2T   = (u16*)(ws + 33554432);     // 8 MiB
  u16* qb    = (u16*)(ws + 41943040);     // q,k,v contiguous: 3 x 16 MiB
  u16* kb    = (u16*)(ws + 58720256);
  u16* vb    = (u16*)(ws + 75497472);
  u16* ctxE  = (u16*)(ws + 92274688);     // 16 MiB (merged ctx in-place)
  u16* ctxO  = (u16*)(ws + 0);            // aliases xb (dead between qkv and ln2)
  float* bqkv = (float*)(ws + 92274688);  // aliases ctxE start (dead before attn)
  u16* res2  = (u16*)(ws + 109051904);    // 16 MiB bf16 now
  u16* mid   = (u16*)(ws + 41943040);     // 64 MiB, reuses qb..ctx

  dim3 tb(32, 8);
  transpose_cvt<<<dim3(32, 32), tb, 0, stream>>>(wq, wqkvT, 1024, 1024);
  transpose_cvt<<<dim3(32, 32), tb, 0, stream>>>(wk, wqkvT + 1048576, 1024, 1024);
  transpose_cvt<<<dim3(32, 32), tb, 0, stream>>>(wv, wqkvT + 2097152, 1024, 1024);
  transpose_cvt<<<dim3(32, 32), tb, 0, stream>>>(wproj, wpT, 1024, 1024);
  transpose_cvt<<<dim3(128, 32), tb, 0, stream>>>(w1, w1T, 1024, 4096);
  transpose_cvt<<<dim3(32, 128), tb, 0, stream>>>(w2, w2T, 4096, 1024);
  concat3<<<12, 256, 0, stream>>>(bq, bk, bv, bqkv);

  ln_kernel<0><<<8192, 256, 0, stream>>>(hidden, ln1_g, ln1_b, xb);

  gemm8<0><<<384, 512, 0, stream>>>(xb, wqkvT, bqkv, nullptr, qb, 8192, 3072, 1024);

  attn_kernel<<<512, 256, 0, stream>>>(qb, kb, vb, ctxE, ctxO);
  merge_kernel<<<4096, 256, 0, stream>>>(ctxE, ctxO, ctxE);

  gemmW<1><<<256, 512, 0, stream>>>(ctxE, wpT, bproj, hidden, res2, 8192, 1024, 1024);

  ln_kernel<1><<<8192, 256, 0, stream>>>(res2, ln2_g, ln2_b, xb);

  gemm8<2><<<512, 512, 0, stream>>>(xb, w1T, b1, nullptr, mid, 8192, 4096, 1024);
  gemmW<3><<<256, 512, 0, stream>>>(mid, w2T, b2, res2, (float*)d_out, 8192, 1024, 4096);
}